// Round 11
// baseline (102.666 us; speedup 1.0000x reference)
//
#include <hip/hip_runtime.h>
#include <hip/hip_bf16.h>
#include <math.h>

typedef float  f32x4  __attribute__((ext_vector_type(4)));
typedef short  s16x8  __attribute__((ext_vector_type(8)));
typedef unsigned int u32x4 __attribute__((ext_vector_type(4)));

constexpr int kNRays = 16384;
constexpr int kOffDepth   = kNRays * 3;
constexpr int kOffAcc     = kOffDepth + kNRays;
constexpr int kOffWeights = kOffAcc + kNRays;

// A-fragment regions (ushort offsets) -- same chained layout as r10.
constexpr int kAg0 = 0;
constexpr int kAg1 = 2048;
constexpr int kAd  = 6144;
constexpr int kAc0 = 7168;
constexpr int kAc1 = 9216;
constexpr int kAc2 = 13312;
constexpr int kAch = 17408;
constexpr int kAF  = 18432;
constexpr int kPrepTotal = kAF + 32;
constexpr size_t kFeatOff = 65536;   // byte offset of feature dump in d_ws

__device__ __forceinline__ ushort f2bf(float x) {
    unsigned u = __float_as_uint(x);
    return (ushort)((u + 0x7FFFu + ((u >> 16) & 1u)) >> 16);
}
__device__ __forceinline__ unsigned pk2(float lo, float hi) {
    __hip_bfloat162 hh = __float22bfloat162_rn(float2{lo, hi});
    return *reinterpret_cast<unsigned*>(&hh);
}
__device__ __forceinline__ float sel4(float v0, float v1, float v2, float v3, int s) {
    float a = (s & 1) ? v1 : v0;
    float b = (s & 1) ? v3 : v2;
    return (s & 2) ? b : a;
}
__device__ __forceinline__ float wave_sum(float v) {
#pragma unroll
    for (int off = 32; off > 0; off >>= 1) v += __shfl_xor(v, off, 64);
    return v;
}

__global__ __launch_bounds__(256) void prep_weights(
    const float* __restrict__ Wg0, const float* __restrict__ Wg1,
    const float* __restrict__ Wd,  const float* __restrict__ Wc0,
    const float* __restrict__ Wc1, const float* __restrict__ Wc2,
    const float* __restrict__ Wch, const float* __restrict__ bd,
    const float* __restrict__ bch, ushort* __restrict__ ws)
{
    const int i = blockIdx.x * 256 + threadIdx.x;
    if (i >= kPrepTotal) return;
    if (i >= kAF) {
        float* fb = (float*)(ws + kAF);
        const int t = i - kAF;
        float v = 0.f;
        if (t < 16) v = (t < 15) ? bd[t + 1] : bd[0];
        else { const int tt = t - 16; if (tt < 3) v = bch[tt]; }
        fb[t] = v;
        return;
    }
    const float* W; int KTP, base, mode = 0;
    if (i < kAg1)      { W = Wg0; KTP = 1; base = kAg0; }
    else if (i < kAd)  { W = Wg1; KTP = 2; base = kAg1; }
    else if (i < kAc0) { W = Wd;  KTP = 2; base = kAd;  mode = 1; }
    else if (i < kAc1) { W = Wc0; KTP = 1; base = kAc0; mode = 2; }
    else if (i < kAc2) { W = Wc1; KTP = 2; base = kAc1; }
    else if (i < kAch) { W = Wc2; KTP = 2; base = kAc2; }
    else               { W = Wch; KTP = 2; base = kAch; mode = 3; }
    const int r = i - base;
    const int e = r & 7, l = (r >> 3) & 63, f = r >> 9;
    const int kt = f % KTP, mt = f / KTP;
    const int g = (l >> 4) & 3, c = l & 15;
    const int fr = 32 * kt + ((e < 4) ? (4 * g + e) : (16 + 4 * g + (e - 4)));
    const int m = 16 * mt + c;
    float w = 0.f;
    if (mode == 0)      w = W[fr * 64 + m];
    else if (mode == 1) w = (m < 15) ? W[fr * 16 + m + 1] : W[fr * 16];
    else if (mode == 2) w = (fr < 24) ? W[fr * 64 + m] : 0.f;
    else                w = (m < 3) ? W[fr * 3 + m] : 0.f;
    ws[i] = f2bf(w);
}

// ---- Phase 1: pure gather at high occupancy. thread t = ray*64 + sample ----
// Writes 4 x u32x4 per sample in the permuted order phase 2 consumes:
// q0={lv0,1,8,9} q1={lv2,3,10,11} q2={lv4,5,12,13} q3={lv6,7,14,15}
__global__ __launch_bounds__(256, 8) void gather_kernel(
    const float* __restrict__ rays_o, const float* __restrict__ rays_d,
    const float* __restrict__ tables, u32x4* __restrict__ feat4)
{
    const int t = blockIdx.x * 256 + threadIdx.x;
    const int ray = t >> 6, s = t & 63;
    const float ox = rays_o[ray * 3 + 0], oy = rays_o[ray * 3 + 1], oz = rays_o[ray * 3 + 2];
    const float dx = rays_d[ray * 3 + 0], dy = rays_d[ray * 3 + 1], dz = rays_d[ray * 3 + 2];
    const float zs = fmaf(1.4f, (float)s * (1.0f / 63.0f), 0.1f);
    const float px = fmaf(dx, zs, ox), py = fmaf(dy, zs, oy), pz = fmaf(dz, zs, oz);

    const float2* __restrict__ tb = (const float2*)tables;
    unsigned dw[16];
#pragma unroll
    for (int lv = 0; lv < 16; ++lv) {
        const float res = (float)(32 << lv);
        const float rm1 = res - 1.0f;
        const float hf = 0.5f * rm1;
        const float sx = __builtin_amdgcn_fmed3f(fmaf(px, hf, hf), 0.f, rm1);
        const float sy = __builtin_amdgcn_fmed3f(fmaf(py, hf, hf), 0.f, rm1);
        const float sz = __builtin_amdgcn_fmed3f(fmaf(pz, hf, hf), 0.f, rm1);
        const float idxf = fmaf(sx, res * res, fmaf(sy, res, sz));
        const float szm1 = (lv == 0) ? 32767.f : (lv == 1) ? 262143.f : 524287.f;
        const unsigned idx = (unsigned)(int)fminf(idxf, szm1);
        const float2 f2 = tb[((unsigned)lv << 19) + idx];
        dw[lv] = pk2(f2.x, f2.y);
    }
    feat4[t * 4 + 0] = (u32x4){ dw[0], dw[1], dw[8],  dw[9]  };
    feat4[t * 4 + 1] = (u32x4){ dw[2], dw[3], dw[10], dw[11] };
    feat4[t * 4 + 2] = (u32x4){ dw[4], dw[5], dw[12], dw[13] };
    feat4[t * 4 + 3] = (u32x4){ dw[6], dw[7], dw[14], dw[15] };
}

// 64->64 layer: D==B chaining, bias as MFMA C operand (r10 layout).
template<int KTP, bool RELU>
__device__ __forceinline__ void layerX(const u32x4 (*__restrict__ Bi)[4],
                                       const ushort* __restrict__ Aws,
                                       const float* __restrict__ bias,
                                       int g4, int lane, u32x4 (*__restrict__ Bo)[4]) {
#pragma unroll
    for (int mt = 0; mt < 4; ++mt) {
        const s16x8 A0 = *(const s16x8*)&Aws[((mt * KTP + 0) * 64 + lane) * 8];
        s16x8 A1;
        if constexpr (KTP == 2) A1 = *(const s16x8*)&Aws[((mt * KTP + 1) * 64 + lane) * 8];
        const f32x4 C = *(const f32x4*)(bias + 16 * mt + g4);
#pragma unroll
        for (int nt = 0; nt < 4; ++nt) {
            f32x4 acc = __builtin_amdgcn_mfma_f32_16x16x32_bf16(
                A0, __builtin_bit_cast(s16x8, Bi[0][nt]), C, 0, 0, 0);
            if constexpr (KTP == 2)
                acc = __builtin_amdgcn_mfma_f32_16x16x32_bf16(
                    A1, __builtin_bit_cast(s16x8, Bi[1][nt]), acc, 0, 0, 0);
            float x0 = acc.x, x1 = acc.y, x2 = acc.z, x3 = acc.w;
            if constexpr (RELU) {
                x0 = fmaxf(x0, 0.f); x1 = fmaxf(x1, 0.f);
                x2 = fmaxf(x2, 0.f); x3 = fmaxf(x3, 0.f);
            }
            Bo[mt >> 1][nt][2 * (mt & 1)]     = pk2(x0, x1);
            Bo[mt >> 1][nt][2 * (mt & 1) + 1] = pk2(x2, x3);
        }
    }
}

// ---- Phase 2: MLP + render; gather replaced by coalesced feature loads ----
__global__ __launch_bounds__(256, 3) void mlp_kernel(
    const float* __restrict__ rays_d, const ushort* __restrict__ ws,
    const u32x4* __restrict__ feat4,
    const float* __restrict__ bg0, const float* __restrict__ bg1,
    const float* __restrict__ bc0, const float* __restrict__ bc1,
    const float* __restrict__ bc2, float* __restrict__ out)
{
    const int tid  = threadIdx.x;
    const int wid  = tid >> 6;
    const int lane = tid & 63;
    const int c16  = lane & 15;
    const int g    = lane >> 4;
    const int g4   = 4 * g;
    const int ray  = blockIdx.x * 4 + wid;

    const float dx = rays_d[ray * 3 + 0], dy = rays_d[ray * 3 + 1], dz = rays_d[ray * 3 + 2];
    const float step = 1.0f / 63.0f;
    const float z  = 0.1f + 1.4f * ((float)lane * step);
    const float zn = 0.1f + 1.4f * ((float)(lane + 1) * step);

    u32x4 B0[1][4];
#pragma unroll
    for (int nt = 0; nt < 4; ++nt)
        B0[0][nt] = feat4[(ray * 64 + nt * 16 + c16) * 4 + g];

    u32x4 B1[2][4], B2[2][4];
    layerX<1, true>(B0, ws + kAg0, bg0, g4, lane, B1);
    layerX<2, true>(B1, ws + kAg1, bg1, g4, lane, B2);

    const float* fb = (const float*)(ws + kAF);
    f32x4 accd[4];
    {
        const s16x8 A0 = *(const s16x8*)&ws[kAd + (0 * 64 + lane) * 8];
        const s16x8 A1 = *(const s16x8*)&ws[kAd + (1 * 64 + lane) * 8];
        const f32x4 Cd = *(const f32x4*)(fb + g4);
#pragma unroll
        for (int nt = 0; nt < 4; ++nt) {
            f32x4 a = __builtin_amdgcn_mfma_f32_16x16x32_bf16(
                A0, __builtin_bit_cast(s16x8, B2[0][nt]), Cd, 0, 0, 0);
            a = __builtin_amdgcn_mfma_f32_16x16x32_bf16(
                A1, __builtin_bit_cast(s16x8, B2[1][nt]), a, 0, 0, 0);
            accd[nt] = a;
        }
    }
    const float lgit = sel4(__shfl(accd[0].w, 48 + c16, 64),
                            __shfl(accd[1].w, 48 + c16, 64),
                            __shfl(accd[2].w, 48 + c16, 64),
                            __shfl(accd[3].w, 48 + c16, 64), g);
    const float dxy = dx * dy, dxz = dx * dz, dyz = dy * dz;
    const float dqq = dx * dx - dy * dy, dzz = 3.f * dz * dz - 1.f;
    const unsigned sh0 = pk2(sel4(dx, dxz, 0.f, 0.f, g), sel4(dy, dyz, 0.f, 0.f, g));
    const unsigned sh1 = pk2(sel4(dz, dqq, 0.f, 0.f, g), sel4(dxy, dzz, 0.f, 0.f, g));
    u32x4 Bc0[1][4];
#pragma unroll
    for (int nt = 0; nt < 4; ++nt) {
        const f32x4 a = accd[nt];
        const float a3 = (g == 3) ? 0.5f : a.w;
        Bc0[0][nt][0] = pk2(a.x, a.y);
        Bc0[0][nt][1] = pk2(a.z, a3);
        Bc0[0][nt][2] = sh0;
        Bc0[0][nt][3] = sh1;
    }

    u32x4 B3[2][4], B4[2][4], B5[2][4];
    layerX<1, true>(Bc0, ws + kAc0, bc0, g4, lane, B3);
    layerX<2, true>(B3,  ws + kAc1, bc1, g4, lane, B4);
    layerX<2, true>(B4,  ws + kAc2, bc2, g4, lane, B5);

    f32x4 acch[4];
    {
        const s16x8 A0 = *(const s16x8*)&ws[kAch + (0 * 64 + lane) * 8];
        const s16x8 A1 = *(const s16x8*)&ws[kAch + (1 * 64 + lane) * 8];
        const f32x4 Cc = *(const f32x4*)(fb + 16 + g4);
#pragma unroll
        for (int nt = 0; nt < 4; ++nt) {
            f32x4 a = __builtin_amdgcn_mfma_f32_16x16x32_bf16(
                A0, __builtin_bit_cast(s16x8, B5[0][nt]), Cc, 0, 0, 0);
            a = __builtin_amdgcn_mfma_f32_16x16x32_bf16(
                A1, __builtin_bit_cast(s16x8, B5[1][nt]), a, 0, 0, 0);
            acch[nt] = a;
        }
    }
    const float lr  = sel4(__shfl(acch[0].x, c16, 64), __shfl(acch[1].x, c16, 64),
                           __shfl(acch[2].x, c16, 64), __shfl(acch[3].x, c16, 64), g);
    const float lgr = sel4(__shfl(acch[0].y, c16, 64), __shfl(acch[1].y, c16, 64),
                           __shfl(acch[2].y, c16, 64), __shfl(acch[3].y, c16, 64), g);
    const float lb  = sel4(__shfl(acch[0].z, c16, 64), __shfl(acch[1].z, c16, 64),
                           __shfl(acch[2].z, c16, 64), __shfl(acch[3].z, c16, 64), g);

    const float cr = 1.f / (1.f + expf(-lr));
    const float cg = 1.f / (1.f + expf(-lgr));
    const float cb = 1.f / (1.f + expf(-lb));
    const float gx = lgit - 1.0f;
    const float density = fmaxf(gx, 0.f) + log1pf(expf(-fabsf(gx)));

    const float dnorm = sqrtf(dx * dx + dy * dy + dz * dz);
    float dist = (lane < 63) ? (zn - z) : 1e10f;
    dist *= dnorm;
    const float alpha = 1.0f - expf(-density * dist);
    float f = 1.0f - alpha + 1e-10f;
#pragma unroll
    for (int off = 1; off < 64; off <<= 1) {
        const float gg = __shfl_up(f, off, 64);
        if (lane >= off) f *= gg;
    }
    float T = __shfl_up(f, 1, 64);
    if (lane == 0) T = 1.0f;
    const float w = alpha * T;

    out[kOffWeights + ray * 64 + lane] = w;
    const float sr = wave_sum(w * cr);
    const float sg = wave_sum(w * cg);
    const float sb = wave_sum(w * cb);
    const float sd = wave_sum(w * z);
    const float sa = wave_sum(w);
    if (lane == 0) {
        out[ray * 3 + 0] = sr;
        out[ray * 3 + 1] = sg;
        out[ray * 3 + 2] = sb;
        out[kOffDepth + ray] = sd;
        out[kOffAcc + ray]   = sa;
    }
}

// ---- Fallback: r10 fused kernel (used if ws_size can't hold the feature dump) ----
__global__ __launch_bounds__(256, 3) void nerf_fused_kernel(
    const float* __restrict__ rays_o, const float* __restrict__ rays_d,
    const float* __restrict__ tables, const ushort* __restrict__ ws,
    const float* __restrict__ bg0, const float* __restrict__ bg1,
    const float* __restrict__ bc0, const float* __restrict__ bc1,
    const float* __restrict__ bc2, float* __restrict__ out)
{
    const int tid  = threadIdx.x;
    const int wid  = tid >> 6;
    const int lane = tid & 63;
    const int c16  = lane & 15;
    const int g    = lane >> 4;
    const int g4   = 4 * g;
    const int ray  = blockIdx.x * 4 + wid;

    const float ox = rays_o[ray * 3 + 0], oy = rays_o[ray * 3 + 1], oz = rays_o[ray * 3 + 2];
    const float dx = rays_d[ray * 3 + 0], dy = rays_d[ray * 3 + 1], dz = rays_d[ray * 3 + 2];
    const float step = 1.0f / 63.0f;
    const float z  = 0.1f + 1.4f * ((float)lane * step);
    const float zn = 0.1f + 1.4f * ((float)(lane + 1) * step);

    const float2* __restrict__ tb = (const float2*)tables;
    u32x4 B0[1][4];
#pragma unroll
    for (int nt = 0; nt < 4; ++nt) {
        const int s = nt * 16 + c16;
        const float ts = (float)s * step;
        const float zs = fmaf(1.4f, ts, 0.1f);
        const float px = fmaf(dx, zs, ox), py = fmaf(dy, zs, oy), pz = fmaf(dz, zs, oz);
        u32x4 val;
#pragma unroll
        for (int j = 0; j < 4; ++j) {
            const int lv = (j < 2) ? (2 * g + j) : (8 + 2 * g + (j - 2));
            const float res = (float)(32 << lv);
            const float rm1 = res - 1.0f;
            const float hf = 0.5f * rm1;
            const float sx = __builtin_amdgcn_fmed3f(fmaf(px, hf, hf), 0.f, rm1);
            const float sy = __builtin_amdgcn_fmed3f(fmaf(py, hf, hf), 0.f, rm1);
            const float sz = __builtin_amdgcn_fmed3f(fmaf(pz, hf, hf), 0.f, rm1);
            const float idxf = fmaf(sx, res * res, fmaf(sy, res, sz));
            const float szm1 = (lv == 0) ? 32767.f : (lv == 1) ? 262143.f : 524287.f;
            const unsigned idx = (unsigned)(int)fminf(idxf, szm1);
            const float2 f2 = tb[((unsigned)lv << 19) + idx];
            val[j] = pk2(f2.x, f2.y);
        }
        B0[0][nt] = val;
    }

    u32x4 B1[2][4], B2[2][4];
    layerX<1, true>(B0, ws + kAg0, bg0, g4, lane, B1);
    layerX<2, true>(B1, ws + kAg1, bg1, g4, lane, B2);

    const float* fb = (const float*)(ws + kAF);
    f32x4 accd[4];
    {
        const s16x8 A0 = *(const s16x8*)&ws[kAd + (0 * 64 + lane) * 8];
        const s16x8 A1 = *(const s16x8*)&ws[kAd + (1 * 64 + lane) * 8];
        const f32x4 Cd = *(const f32x4*)(fb + g4);
#pragma unroll
        for (int nt = 0; nt < 4; ++nt) {
            f32x4 a = __builtin_amdgcn_mfma_f32_16x16x32_bf16(
                A0, __builtin_bit_cast(s16x8, B2[0][nt]), Cd, 0, 0, 0);
            a = __builtin_amdgcn_mfma_f32_16x16x32_bf16(
                A1, __builtin_bit_cast(s16x8, B2[1][nt]), a, 0, 0, 0);
            accd[nt] = a;
        }
    }
    const float lgit = sel4(__shfl(accd[0].w, 48 + c16, 64),
                            __shfl(accd[1].w, 48 + c16, 64),
                            __shfl(accd[2].w, 48 + c16, 64),
                            __shfl(accd[3].w, 48 + c16, 64), g);
    const float dxy = dx * dy, dxz = dx * dz, dyz = dy * dz;
    const float dqq = dx * dx - dy * dy, dzz = 3.f * dz * dz - 1.f;
    const unsigned sh0 = pk2(sel4(dx, dxz, 0.f, 0.f, g), sel4(dy, dyz, 0.f, 0.f, g));
    const unsigned sh1 = pk2(sel4(dz, dqq, 0.f, 0.f, g), sel4(dxy, dzz, 0.f, 0.f, g));
    u32x4 Bc0[1][4];
#pragma unroll
    for (int nt = 0; nt < 4; ++nt) {
        const f32x4 a = accd[nt];
        const float a3 = (g == 3) ? 0.5f : a.w;
        Bc0[0][nt][0] = pk2(a.x, a.y);
        Bc0[0][nt][1] = pk2(a.z, a3);
        Bc0[0][nt][2] = sh0;
        Bc0[0][nt][3] = sh1;
    }

    u32x4 B3[2][4], B4[2][4], B5[2][4];
    layerX<1, true>(Bc0, ws + kAc0, bc0, g4, lane, B3);
    layerX<2, true>(B3,  ws + kAc1, bc1, g4, lane, B4);
    layerX<2, true>(B4,  ws + kAc2, bc2, g4, lane, B5);

    f32x4 acch[4];
    {
        const s16x8 A0 = *(const s16x8*)&ws[kAch + (0 * 64 + lane) * 8];
        const s16x8 A1 = *(const s16x8*)&ws[kAch + (1 * 64 + lane) * 8];
        const f32x4 Cc = *(const f32x4*)(fb + 16 + g4);
#pragma unroll
        for (int nt = 0; nt < 4; ++nt) {
            f32x4 a = __builtin_amdgcn_mfma_f32_16x16x32_bf16(
                A0, __builtin_bit_cast(s16x8, B5[0][nt]), Cc, 0, 0, 0);
            a = __builtin_amdgcn_mfma_f32_16x16x32_bf16(
                A1, __builtin_bit_cast(s16x8, B5[1][nt]), a, 0, 0, 0);
            acch[nt] = a;
        }
    }
    const float lr  = sel4(__shfl(acch[0].x, c16, 64), __shfl(acch[1].x, c16, 64),
                           __shfl(acch[2].x, c16, 64), __shfl(acch[3].x, c16, 64), g);
    const float lgr = sel4(__shfl(acch[0].y, c16, 64), __shfl(acch[1].y, c16, 64),
                           __shfl(acch[2].y, c16, 64), __shfl(acch[3].y, c16, 64), g);
    const float lb  = sel4(__shfl(acch[0].z, c16, 64), __shfl(acch[1].z, c16, 64),
                           __shfl(acch[2].z, c16, 64), __shfl(acch[3].z, c16, 64), g);

    const float cr = 1.f / (1.f + expf(-lr));
    const float cg = 1.f / (1.f + expf(-lgr));
    const float cb = 1.f / (1.f + expf(-lb));
    const float gx = lgit - 1.0f;
    const float density = fmaxf(gx, 0.f) + log1pf(expf(-fabsf(gx)));

    const float dnorm = sqrtf(dx * dx + dy * dy + dz * dz);
    float dist = (lane < 63) ? (zn - z) : 1e10f;
    dist *= dnorm;
    const float alpha = 1.0f - expf(-density * dist);
    float f = 1.0f - alpha + 1e-10f;
#pragma unroll
    for (int off = 1; off < 64; off <<= 1) {
        const float gg = __shfl_up(f, off, 64);
        if (lane >= off) f *= gg;
    }
    float T = __shfl_up(f, 1, 64);
    if (lane == 0) T = 1.0f;
    const float w = alpha * T;

    out[kOffWeights + ray * 64 + lane] = w;
    const float sr = wave_sum(w * cr);
    const float sg = wave_sum(w * cg);
    const float sb = wave_sum(w * cb);
    const float sd = wave_sum(w * z);
    const float sa = wave_sum(w);
    if (lane == 0) {
        out[ray * 3 + 0] = sr;
        out[ray * 3 + 1] = sg;
        out[ray * 3 + 2] = sb;
        out[kOffDepth + ray] = sd;
        out[kOffAcc + ray]   = sa;
    }
}

extern "C" void kernel_launch(void* const* d_in, const int* in_sizes, int n_in,
                              void* d_out, int out_size, void* d_ws, size_t ws_size,
                              hipStream_t stream) {
    const float* rays_o = (const float*)d_in[0];
    const float* rays_d = (const float*)d_in[1];
    const float* tables = (const float*)d_in[2];
    const float* Wg0 = (const float*)d_in[3];
    const float* bg0 = (const float*)d_in[4];
    const float* Wg1 = (const float*)d_in[5];
    const float* bg1 = (const float*)d_in[6];
    const float* Wd  = (const float*)d_in[7];
    const float* bd  = (const float*)d_in[8];
    const float* Wc0 = (const float*)d_in[9];
    const float* bc0 = (const float*)d_in[10];
    const float* Wc1 = (const float*)d_in[11];
    const float* bc1 = (const float*)d_in[12];
    const float* Wc2 = (const float*)d_in[13];
    const float* bc2 = (const float*)d_in[14];
    const float* Wch = (const float*)d_in[15];
    const float* bch = (const float*)d_in[16];
    float* out = (float*)d_out;
    ushort* wsp = (ushort*)d_ws;

    prep_weights<<<dim3((kPrepTotal + 255) / 256), dim3(256), 0, stream>>>(
        Wg0, Wg1, Wd, Wc0, Wc1, Wc2, Wch, bd, bch, wsp);

    const size_t need = kFeatOff + (size_t)kNRays * 64 * 64;   // ~67.2 MB
    if (ws_size >= need) {
        u32x4* feat4 = (u32x4*)((char*)d_ws + kFeatOff);
        gather_kernel<<<dim3(kNRays * 64 / 256), dim3(256), 0, stream>>>(
            rays_o, rays_d, tables, feat4);
        mlp_kernel<<<dim3(kNRays / 4), dim3(256), 0, stream>>>(
            rays_d, wsp, feat4, bg0, bg1, bc0, bc1, bc2, out);
    } else {
        nerf_fused_kernel<<<dim3(kNRays / 4), dim3(256), 0, stream>>>(
            rays_o, rays_d, tables, wsp, bg0, bg1, bc0, bc1, bc2, out);
    }
}

// Round 12
// 83.594 us; speedup vs baseline: 1.2282x; 1.2282x over previous
//
#include <hip/hip_runtime.h>
#include <hip/hip_bf16.h>
#include <math.h>

typedef float  f32x4  __attribute__((ext_vector_type(4)));
typedef short  s16x8  __attribute__((ext_vector_type(8)));
typedef unsigned int u32x4 __attribute__((ext_vector_type(4)));

constexpr int kNRays = 16384;
constexpr int kOffDepth   = kNRays * 3;
constexpr int kOffAcc     = kOffDepth + kNRays;
constexpr int kOffWeights = kOffAcc + kNRays;

// A-fragment regions (ushort offsets) -- r10 chained layout.
constexpr int kAg0 = 0;
constexpr int kAg1 = 2048;
constexpr int kAd  = 6144;
constexpr int kAc0 = 7168;
constexpr int kAc1 = 9216;
constexpr int kAc2 = 13312;
constexpr int kAch = 17408;
constexpr int kAF  = 18432;
constexpr int kPrepTotal = kAF + 32;

__device__ __forceinline__ ushort f2bf(float x) {
    unsigned u = __float_as_uint(x);
    return (ushort)((u + 0x7FFFu + ((u >> 16) & 1u)) >> 16);
}
__device__ __forceinline__ unsigned pk2(float lo, float hi) {
    __hip_bfloat162 hh = __float22bfloat162_rn(float2{lo, hi});
    return *reinterpret_cast<unsigned*>(&hh);
}
__device__ __forceinline__ float sel4(float v0, float v1, float v2, float v3, int s) {
    float a = (s & 1) ? v1 : v0;
    float b = (s & 1) ? v3 : v2;
    return (s & 2) ? b : a;
}
__device__ __forceinline__ float wave_sum(float v) {
#pragma unroll
    for (int off = 32; off > 0; off >>= 1) v += __shfl_xor(v, off, 64);
    return v;
}

__global__ __launch_bounds__(256) void prep_weights(
    const float* __restrict__ Wg0, const float* __restrict__ Wg1,
    const float* __restrict__ Wd,  const float* __restrict__ Wc0,
    const float* __restrict__ Wc1, const float* __restrict__ Wc2,
    const float* __restrict__ Wch, const float* __restrict__ bd,
    const float* __restrict__ bch, ushort* __restrict__ ws)
{
    const int i = blockIdx.x * 256 + threadIdx.x;
    if (i >= kPrepTotal) return;
    if (i >= kAF) {
        float* fb = (float*)(ws + kAF);
        const int t = i - kAF;
        float v = 0.f;
        if (t < 16) v = (t < 15) ? bd[t + 1] : bd[0];
        else { const int tt = t - 16; if (tt < 3) v = bch[tt]; }
        fb[t] = v;
        return;
    }
    const float* W; int KTP, base, mode = 0;
    if (i < kAg1)      { W = Wg0; KTP = 1; base = kAg0; }
    else if (i < kAd)  { W = Wg1; KTP = 2; base = kAg1; }
    else if (i < kAc0) { W = Wd;  KTP = 2; base = kAd;  mode = 1; }
    else if (i < kAc1) { W = Wc0; KTP = 1; base = kAc0; mode = 2; }
    else if (i < kAc2) { W = Wc1; KTP = 2; base = kAc1; }
    else if (i < kAch) { W = Wc2; KTP = 2; base = kAc2; }
    else               { W = Wch; KTP = 2; base = kAch; mode = 3; }
    const int r = i - base;
    const int e = r & 7, l = (r >> 3) & 63, f = r >> 9;
    const int kt = f % KTP, mt = f / KTP;
    const int g = (l >> 4) & 3, c = l & 15;
    const int fr = 32 * kt + ((e < 4) ? (4 * g + e) : (16 + 4 * g + (e - 4)));
    const int m = 16 * mt + c;
    float w = 0.f;
    if (mode == 0)      w = W[fr * 64 + m];
    else if (mode == 1) w = (m < 15) ? W[fr * 16 + m + 1] : W[fr * 16];
    else if (mode == 2) w = (fr < 24) ? W[fr * 64 + m] : 0.f;
    else                w = (m < 3) ? W[fr * 3 + m] : 0.f;
    ws[i] = f2bf(w);
}

// Prefetch NF A-fragments for a layer into registers.
template<int NF>
__device__ __forceinline__ void loadAfr(const ushort* __restrict__ Aws, int lane, s16x8* A) {
#pragma unroll
    for (int f = 0; f < NF; ++f)
        A[f] = *(const s16x8*)&Aws[(f * 64 + lane) * 8];
}

// 64->64 layer compute from PRELOADED A regs; bias JIT via C operand; D==B chaining.
template<int KTP, bool RELU>
__device__ __forceinline__ void compute64(const s16x8* __restrict__ A,
                                          const float* __restrict__ bias,
                                          int g4,
                                          const u32x4 (*__restrict__ Bi)[4],
                                          u32x4 (*__restrict__ Bo)[4]) {
#pragma unroll
    for (int mt = 0; mt < 4; ++mt) {
        const f32x4 C = *(const f32x4*)(bias + 16 * mt + g4);
#pragma unroll
        for (int nt = 0; nt < 4; ++nt) {
            f32x4 acc = __builtin_amdgcn_mfma_f32_16x16x32_bf16(
                A[mt * KTP + 0], __builtin_bit_cast(s16x8, Bi[0][nt]), C, 0, 0, 0);
            if constexpr (KTP == 2)
                acc = __builtin_amdgcn_mfma_f32_16x16x32_bf16(
                    A[mt * KTP + 1], __builtin_bit_cast(s16x8, Bi[1][nt]), acc, 0, 0, 0);
            float x0 = acc.x, x1 = acc.y, x2 = acc.z, x3 = acc.w;
            if constexpr (RELU) {
                x0 = fmaxf(x0, 0.f); x1 = fmaxf(x1, 0.f);
                x2 = fmaxf(x2, 0.f); x3 = fmaxf(x3, 0.f);
            }
            Bo[mt >> 1][nt][2 * (mt & 1)]     = pk2(x0, x1);
            Bo[mt >> 1][nt][2 * (mt & 1) + 1] = pk2(x2, x3);
        }
    }
}

__global__ __launch_bounds__(256, 3) void nerf_fused_kernel(
    const float* __restrict__ rays_o, const float* __restrict__ rays_d,
    const float* __restrict__ tables, const ushort* __restrict__ ws,
    const float* __restrict__ bg0, const float* __restrict__ bg1,
    const float* __restrict__ bc0, const float* __restrict__ bc1,
    const float* __restrict__ bc2, float* __restrict__ out)
{
    const int tid  = threadIdx.x;
    const int wid  = tid >> 6;
    const int lane = tid & 63;
    const int c16  = lane & 15;
    const int g    = lane >> 4;
    const int g4   = 4 * g;
    const int ray  = blockIdx.x * 4 + wid;

    const float ox = rays_o[ray * 3 + 0], oy = rays_o[ray * 3 + 1], oz = rays_o[ray * 3 + 2];
    const float dx = rays_d[ray * 3 + 0], dy = rays_d[ray * 3 + 1], dz = rays_d[ray * 3 + 2];
    const float step = 1.0f / 63.0f;
    const float z  = 0.1f + 1.4f * ((float)lane * step);
    const float zn = 0.1f + 1.4f * ((float)(lane + 1) * step);

    // ---- issue all 16 scattered gather loads first (longest latency) ----
    const float2* __restrict__ tb = (const float2*)tables;
    float2 f2r[4][4];
#pragma unroll
    for (int nt = 0; nt < 4; ++nt) {
        const int s = nt * 16 + c16;
        const float ts = (float)s * step;
        const float zs = fmaf(1.4f, ts, 0.1f);
        const float px = fmaf(dx, zs, ox), py = fmaf(dy, zs, oy), pz = fmaf(dz, zs, oz);
#pragma unroll
        for (int j = 0; j < 4; ++j) {
            const int lv = (j < 2) ? (2 * g + j) : (8 + 2 * g + (j - 2));
            const float res = (float)(32 << lv);
            const float rm1 = res - 1.0f;
            const float hf = 0.5f * rm1;
            const float sx = __builtin_amdgcn_fmed3f(fmaf(px, hf, hf), 0.f, rm1);
            const float sy = __builtin_amdgcn_fmed3f(fmaf(py, hf, hf), 0.f, rm1);
            const float sz = __builtin_amdgcn_fmed3f(fmaf(pz, hf, hf), 0.f, rm1);
            const float idxf = fmaf(sx, res * res, fmaf(sy, res, sz));
            const float szm1 = (lv == 0) ? 32767.f : (lv == 1) ? 262143.f : 524287.f;
            const unsigned idx = (unsigned)(int)fminf(idxf, szm1);
            f2r[nt][j] = tb[((unsigned)lv << 19) + idx];
        }
    }

    // ---- prefetch g0 + g1 weights while gathers are in flight ----
    s16x8 A0r[4], A1r[8];
    loadAfr<4>(ws + kAg0, lane, A0r);
    loadAfr<8>(ws + kAg1, lane, A1r);

    // ---- pack B0 (first point that waits on the gather loads) ----
    u32x4 B0[1][4];
#pragma unroll
    for (int nt = 0; nt < 4; ++nt)
        B0[0][nt] = (u32x4){ pk2(f2r[nt][0].x, f2r[nt][0].y),
                             pk2(f2r[nt][1].x, f2r[nt][1].y),
                             pk2(f2r[nt][2].x, f2r[nt][2].y),
                             pk2(f2r[nt][3].x, f2r[nt][3].y) };

    // ---- g0 (prefetch d during) ----
    u32x4 B1[2][4], B2[2][4];
    compute64<1, true>(A0r, bg0, g4, B0, B1);
    s16x8 A2r[2];
    loadAfr<2>(ws + kAd, lane, A2r);

    // ---- g1 (prefetch c0 during) ----
    compute64<2, true>(A1r, bg1, g4, B1, B2);
    s16x8 A3r[4];
    loadAfr<4>(ws + kAc0, lane, A3r);

    // ---- d: 64 -> 16 (cols rotated; col15 = geo[0] logit), no relu ----
    const float* fb = (const float*)(ws + kAF);
    f32x4 accd[4];
    {
        const f32x4 Cd = *(const f32x4*)(fb + g4);
#pragma unroll
        for (int nt = 0; nt < 4; ++nt) {
            f32x4 a = __builtin_amdgcn_mfma_f32_16x16x32_bf16(
                A2r[0], __builtin_bit_cast(s16x8, B2[0][nt]), Cd, 0, 0, 0);
            a = __builtin_amdgcn_mfma_f32_16x16x32_bf16(
                A2r[1], __builtin_bit_cast(s16x8, B2[1][nt]), a, 0, 0, 0);
            accd[nt] = a;
        }
    }
    // prefetch c1 while finishing d epilogue
    s16x8 A4r[8];
    loadAfr<8>(ws + kAc1, lane, A4r);

    const float lgit = sel4(__shfl(accd[0].w, 48 + c16, 64),
                            __shfl(accd[1].w, 48 + c16, 64),
                            __shfl(accd[2].w, 48 + c16, 64),
                            __shfl(accd[3].w, 48 + c16, 64), g);
    const float dxy = dx * dy, dxz = dx * dz, dyz = dy * dz;
    const float dqq = dx * dx - dy * dy, dzz = 3.f * dz * dz - 1.f;
    const unsigned sh0 = pk2(sel4(dx, dxz, 0.f, 0.f, g), sel4(dy, dyz, 0.f, 0.f, g));
    const unsigned sh1 = pk2(sel4(dz, dqq, 0.f, 0.f, g), sel4(dxy, dzz, 0.f, 0.f, g));
    u32x4 Bc0[1][4];
#pragma unroll
    for (int nt = 0; nt < 4; ++nt) {
        const f32x4 a = accd[nt];
        const float a3 = (g == 3) ? 0.5f : a.w;
        Bc0[0][nt][0] = pk2(a.x, a.y);
        Bc0[0][nt][1] = pk2(a.z, a3);
        Bc0[0][nt][2] = sh0;
        Bc0[0][nt][3] = sh1;
    }

    // ---- c0 (prefetch c2 during) ----
    u32x4 B3[2][4], B4[2][4], B5[2][4];
    compute64<1, true>(A3r, bc0, g4, Bc0, B3);
    s16x8 A5r[8];
    loadAfr<8>(ws + kAc2, lane, A5r);

    // ---- c1 (prefetch ch during) ----
    compute64<2, true>(A4r, bc1, g4, B3, B4);
    s16x8 A6r[2];
    loadAfr<2>(ws + kAch, lane, A6r);

    // ---- c2 ----
    compute64<2, true>(A5r, bc2, g4, B4, B5);

    // ---- ch: 64 -> 3 (M-pad 16) ----
    f32x4 acch[4];
    {
        const f32x4 Cc = *(const f32x4*)(fb + 16 + g4);
#pragma unroll
        for (int nt = 0; nt < 4; ++nt) {
            f32x4 a = __builtin_amdgcn_mfma_f32_16x16x32_bf16(
                A6r[0], __builtin_bit_cast(s16x8, B5[0][nt]), Cc, 0, 0, 0);
            a = __builtin_amdgcn_mfma_f32_16x16x32_bf16(
                A6r[1], __builtin_bit_cast(s16x8, B5[1][nt]), a, 0, 0, 0);
            acch[nt] = a;
        }
    }
    const float lr  = sel4(__shfl(acch[0].x, c16, 64), __shfl(acch[1].x, c16, 64),
                           __shfl(acch[2].x, c16, 64), __shfl(acch[3].x, c16, 64), g);
    const float lgr = sel4(__shfl(acch[0].y, c16, 64), __shfl(acch[1].y, c16, 64),
                           __shfl(acch[2].y, c16, 64), __shfl(acch[3].y, c16, 64), g);
    const float lb  = sel4(__shfl(acch[0].z, c16, 64), __shfl(acch[1].z, c16, 64),
                           __shfl(acch[2].z, c16, 64), __shfl(acch[3].z, c16, 64), g);

    const float cr = 1.f / (1.f + expf(-lr));
    const float cg = 1.f / (1.f + expf(-lgr));
    const float cb = 1.f / (1.f + expf(-lb));
    const float gx = lgit - 1.0f;
    const float density = fmaxf(gx, 0.f) + log1pf(expf(-fabsf(gx)));

    // ---- volume rendering (lane = sample) ----
    const float dnorm = sqrtf(dx * dx + dy * dy + dz * dz);
    float dist = (lane < 63) ? (zn - z) : 1e10f;
    dist *= dnorm;
    const float alpha = 1.0f - expf(-density * dist);
    float f = 1.0f - alpha + 1e-10f;
#pragma unroll
    for (int off = 1; off < 64; off <<= 1) {
        const float gg = __shfl_up(f, off, 64);
        if (lane >= off) f *= gg;
    }
    float T = __shfl_up(f, 1, 64);
    if (lane == 0) T = 1.0f;
    const float w = alpha * T;

    out[kOffWeights + ray * 64 + lane] = w;
    const float sr = wave_sum(w * cr);
    const float sg = wave_sum(w * cg);
    const float sb = wave_sum(w * cb);
    const float sd = wave_sum(w * z);
    const float sa = wave_sum(w);
    if (lane == 0) {
        out[ray * 3 + 0] = sr;
        out[ray * 3 + 1] = sg;
        out[ray * 3 + 2] = sb;
        out[kOffDepth + ray] = sd;
        out[kOffAcc + ray]   = sa;
    }
}

extern "C" void kernel_launch(void* const* d_in, const int* in_sizes, int n_in,
                              void* d_out, int out_size, void* d_ws, size_t ws_size,
                              hipStream_t stream) {
    const float* rays_o = (const float*)d_in[0];
    const float* rays_d = (const float*)d_in[1];
    const float* tables = (const float*)d_in[2];
    const float* Wg0 = (const float*)d_in[3];
    const float* bg0 = (const float*)d_in[4];
    const float* Wg1 = (const float*)d_in[5];
    const float* bg1 = (const float*)d_in[6];
    const float* Wd  = (const float*)d_in[7];
    const float* bd  = (const float*)d_in[8];
    const float* Wc0 = (const float*)d_in[9];
    const float* bc0 = (const float*)d_in[10];
    const float* Wc1 = (const float*)d_in[11];
    const float* bc1 = (const float*)d_in[12];
    const float* Wc2 = (const float*)d_in[13];
    const float* bc2 = (const float*)d_in[14];
    const float* Wch = (const float*)d_in[15];
    const float* bch = (const float*)d_in[16];
    float* out = (float*)d_out;
    ushort* wsp = (ushort*)d_ws;

    prep_weights<<<dim3((kPrepTotal + 255) / 256), dim3(256), 0, stream>>>(
        Wg0, Wg1, Wd, Wc0, Wc1, Wc2, Wch, bd, bch, wsp);

    nerf_fused_kernel<<<dim3(kNRays / 4), dim3(256), 0, stream>>>(
        rays_o, rays_d, tables, wsp, bg0, bg1, bc0, bc1, bc2, out);
}